// Round 3
// baseline (535.715 us; speedup 1.0000x reference)
//
#include <hip/hip_runtime.h>

typedef __bf16 bf16;
typedef bf16 bf16x8 __attribute__((ext_vector_type(8)));
typedef bf16 bf16x4 __attribute__((ext_vector_type(4)));
typedef float f32x4 __attribute__((ext_vector_type(4)));

#define MFMA16(a, b, c) __builtin_amdgcn_mfma_f32_16x16x32_bf16((a), (b), (c), 0, 0, 0)

__device__ __forceinline__ void gload_lds16(const bf16* g, bf16* l) {
  __builtin_amdgcn_global_load_lds(
      (const __attribute__((address_space(1))) void*)g,
      (__attribute__((address_space(3))) void*)l, 16, 0, 0);
}

// ---------------------------------------------------------------------------
// fp32 -> bf16 convert
// ---------------------------------------------------------------------------
__global__ __launch_bounds__(256) void cvt_f32_bf16(const float* __restrict__ src,
                                                    bf16* __restrict__ dst, int n4) {
  int i = blockIdx.x * blockDim.x + threadIdx.x;
  if (i < n4) {
    float4 v = ((const float4*)src)[i];
    bf16x4 o;
    o[0] = (bf16)v.x; o[1] = (bf16)v.y; o[2] = (bf16)v.z; o[3] = (bf16)v.w;
    ((bf16x4*)dst)[i] = o;
  }
}

// ---------------------------------------------------------------------------
// GEMM C = A * B^T (m97 structure, unchanged from R1 — passing)
// ---------------------------------------------------------------------------
template <typename OutT>
__global__ __launch_bounds__(256) void gemm_bt(const bf16* __restrict__ A,
                                               const bf16* __restrict__ B,
                                               OutT* __restrict__ C,
                                               int M, int N, int K) {
  __shared__ __align__(16) bf16 As[128 * 64];
  __shared__ __align__(16) bf16 Bs[128 * 64];
  const int tid = threadIdx.x;
  const int w = tid >> 6, lane = tid & 63;
  const int l15 = lane & 15, quad = lane >> 4;
  const int m0 = blockIdx.y * 128, n0 = blockIdx.x * 128;
  const int wm = (w >> 1) * 64, wn = (w & 1) * 64;

  f32x4 acc[4][4] = {};

  for (int k0 = 0; k0 < K; k0 += 64) {
#pragma unroll
    for (int i = 0; i < 4; i++) {
      int s = w * 256 + i * 64 + lane;
      int row = s >> 3;
      int c8 = (s & 7) ^ (row & 7);
      gload_lds16(A + (size_t)(m0 + row) * K + k0 + c8 * 8, As + (w * 256 + i * 64) * 8);
    }
#pragma unroll
    for (int i = 0; i < 4; i++) {
      int s = w * 256 + i * 64 + lane;
      int row = s >> 3;
      int c8 = (s & 7) ^ (row & 7);
      gload_lds16(B + (size_t)(n0 + row) * K + k0 + c8 * 8, Bs + (w * 256 + i * 64) * 8);
    }
    __syncthreads();

#pragma unroll
    for (int kk = 0; kk < 2; kk++) {
      bf16x8 af[4], bfr[4];
#pragma unroll
      for (int mt = 0; mt < 4; mt++) {
        int row = wm + mt * 16 + l15;
        int slot = row * 8 + ((kk * 4 + quad) ^ (row & 7));
        af[mt] = *(const bf16x8*)(As + slot * 8);
      }
#pragma unroll
      for (int nt = 0; nt < 4; nt++) {
        int row = wn + nt * 16 + l15;
        int slot = row * 8 + ((kk * 4 + quad) ^ (row & 7));
        bfr[nt] = *(const bf16x8*)(Bs + slot * 8);
      }
#pragma unroll
      for (int mt = 0; mt < 4; mt++)
#pragma unroll
        for (int nt = 0; nt < 4; nt++)
          acc[mt][nt] = MFMA16(af[mt], bfr[nt], acc[mt][nt]);
    }
    __syncthreads();
  }

#pragma unroll
  for (int mt = 0; mt < 4; mt++)
#pragma unroll
    for (int nt = 0; nt < 4; nt++) {
      int row = m0 + wm + mt * 16 + quad * 4;
      int col = n0 + wn + nt * 16 + l15;
#pragma unroll
      for (int r = 0; r < 4; r++)
        C[(size_t)(row + r) * N + col] = (OutT)acc[mt][nt][r];
    }
}

// ---------------------------------------------------------------------------
// RMSNorm + RoPE. Q prescaled by D^-0.5 * log2(e) (attention uses exp2 with
// a FIXED max: |score| <= 11.32 by RMSNorm bound, so constant M=12 is safe).
// ---------------------------------------------------------------------------
__global__ __launch_bounds__(256) void normrope(const bf16* __restrict__ QKVb,
                                                const float* __restrict__ cosb,
                                                const float* __restrict__ sinb,
                                                const float* __restrict__ qw,
                                                const float* __restrict__ kw,
                                                bf16* __restrict__ Qb,
                                                bf16* __restrict__ Kb) {
  const int wid = (blockIdx.x * blockDim.x + threadIdx.x) >> 6;
  const int lane = threadIdx.x & 63;
  const int s = wid / 24;
  const int h = wid % 24;
  const bool isq = (h < 16);
  const int col0 = isq ? h * 128 : 2048 + (h - 16) * 128;
  const float* wt = isq ? qw : kw;

  const bf16* row = QKVb + (size_t)s * 4096 + col0;
  float x1 = (float)row[lane];
  float x2 = (float)row[lane + 64];

  float ss = x1 * x1 + x2 * x2;
#pragma unroll
  for (int m = 32; m >= 1; m >>= 1) ss += __shfl_xor(ss, m, 64);
  float rs = rsqrtf(ss * (1.0f / 128.0f) + 1e-6f);

  float c = cosb[(size_t)s * 128 + lane];
  float sn = sinb[(size_t)s * 128 + lane];
  float xn1 = x1 * rs * wt[lane];
  float xn2 = x2 * rs * wt[lane + 64];
  float o1 = xn1 * c - xn2 * sn;
  float o2 = xn2 * c + xn1 * sn;
  // D^-0.5 * log2(e) folded into Q for exp2-based fixed-max softmax
  const float scale = isq ? 0.12751652f : 1.0f;
  o1 *= scale; o2 *= scale;

  bf16* dst = isq ? (Qb + ((size_t)h * 4096 + s) * 128)
                  : (Kb + ((size_t)(h - 16) * 4096 + s) * 128);
  dst[lane] = (bf16)o1;
  dst[lane + 64] = (bf16)o2;
}

// ---------------------------------------------------------------------------
// V transpose: Vt[kvh][d][s] = QKV[s][3072 + kvh*128 + d]
// ---------------------------------------------------------------------------
__global__ __launch_bounds__(256) void vtrans(const bf16* __restrict__ QKVb,
                                              bf16* __restrict__ Vt) {
  __shared__ __align__(16) bf16 T[64 * 136];
  const int kvh = blockIdx.y;
  const int s0 = blockIdx.x * 64;
  const int tid = threadIdx.x;
  for (int g = tid; g < 1024; g += 256) {
    int s = g >> 4, cg = g & 15;
    *(bf16x8*)(T + s * 136 + cg * 8) =
        *(const bf16x8*)(QKVb + (size_t)(s0 + s) * 4096 + 3072 + kvh * 128 + cg * 8);
  }
  __syncthreads();
  for (int g = tid; g < 1024; g += 256) {
    int d = g >> 3, sg = g & 7;
    bf16x8 v;
#pragma unroll
    for (int j = 0; j < 8; j++) v[j] = T[(sg * 8 + j) * 136 + d];
    *(bf16x8*)(Vt + ((size_t)kvh * 128 + d) * 4096 + s0 + sg * 8) = v;
  }
}

// ---------------------------------------------------------------------------
// Sliding-window GQA flash attention, wave-per-tile.
// Block = (head, 64 q). Each wave owns ALL 64 q (4 m-frags) and every 4th
// 32-key tile. K/V frags load directly from global (no staging, no barriers
// in the main loop); V from pre-transposed Vt. Fixed-max exp2 softmax (no
// running max / rescaling). End: linear merge of O (ds_add_f32) and l.
// ---------------------------------------------------------------------------
__global__ __launch_bounds__(256, 2) void attn_kernel(const bf16* __restrict__ Qb,
                                                      const bf16* __restrict__ Kb,
                                                      const bf16* __restrict__ Vt,
                                                      bf16* __restrict__ Ob) {
  const int SEQ = 4096, W = 1024;
  const float MP = 17.312340f;  // 12 * log2(e)
  __shared__ __align__(16) bf16 Qs[64 * 136];     // 17.4 KB
  __shared__ __align__(16) bf16 Ps[4][64 * 40];   // 20.5 KB (per-wave P)
  __shared__ __align__(16) float Obuf[64 * 132];  // 33.8 KB
  __shared__ float lbuf[64];

  const int h = blockIdx.y, kvh = h >> 1;
  const int qb0 = blockIdx.x * 64;
  const int tid = threadIdx.x, w = tid >> 6, lane = tid & 63;
  const int l15 = lane & 15, quad = lane >> 4;

  for (int i = tid; i < 64 * 132; i += 256) Obuf[i] = 0.0f;
  if (tid < 64) lbuf[tid] = 0.0f;
  // stage Q tile (64 x 128, ld=136: b128 reads land 2-way max)
  for (int g = tid; g < 1024; g += 256) {
    int row = g >> 4, cg = g & 15;
    *(bf16x8*)(Qs + row * 136 + cg * 8) =
        *(const bf16x8*)(Qb + ((size_t)h * SEQ + qb0 + row) * 128 + cg * 8);
  }
  __syncthreads();

  f32x4 o[4][8] = {};
  f32x4 lr[4] = {};
  bf16* pw = &Ps[w][0];
  const bf16* kbase0 = Kb + (size_t)kvh * SEQ * 128;
  const bf16* vbase0 = Vt + (size_t)kvh * 128 * SEQ;

  int kstart = qb0 - (W - 1); if (kstart < 0) kstart = 0;
  const int kt0 = kstart >> 5, kt1 = (qb0 + 63) >> 5;

  for (int kt = kt0 + w; kt <= kt1; kt += 4) {
    const int k0 = kt * 32;
    // K B-frags straight from global: lane(n=l15 -> key, quad -> d granule)
    bf16x8 kf[2][4];
    const bf16* kb_ = kbase0 + (size_t)k0 * 128;
#pragma unroll
    for (int c = 0; c < 2; c++)
#pragma unroll
      for (int kb = 0; kb < 4; kb++)
        kf[c][kb] = *(const bf16x8*)(kb_ + (c * 16 + l15) * 128 + kb * 32 + quad * 8);

    const bool full = (k0 + 31 <= qb0) && (k0 > qb0 + 63 - W);

#pragma unroll
    for (int m = 0; m < 4; m++) {
      f32x4 s0 = {}, s1 = {};
#pragma unroll
      for (int kb = 0; kb < 4; kb++) {
        bf16x8 qf = *(const bf16x8*)(Qs + (m * 16 + l15) * 136 + kb * 32 + quad * 8);
        s0 = MFMA16(qf, kf[0][kb], s0);
        s1 = MFMA16(qf, kf[1][kb], s1);
      }
      float p0[4], p1[4];
      if (full) {
#pragma unroll
        for (int r = 0; r < 4; r++) {
          p0[r] = __builtin_amdgcn_exp2f(s0[r] - MP);
          p1[r] = __builtin_amdgcn_exp2f(s1[r] - MP);
        }
      } else {
#pragma unroll
        for (int r = 0; r < 4; r++) {
          int i = qb0 + m * 16 + quad * 4 + r;
          int j0 = k0 + l15, j1 = k0 + 16 + l15;
          p0[r] = (j0 <= i && j0 > i - W) ? __builtin_amdgcn_exp2f(s0[r] - MP) : 0.0f;
          p1[r] = (j1 <= i && j1 > i - W) ? __builtin_amdgcn_exp2f(s1[r] - MP) : 0.0f;
        }
      }
#pragma unroll
      for (int r = 0; r < 4; r++) {
        lr[m][r] += p0[r] + p1[r];
        pw[(m * 16 + quad * 4 + r) * 40 + l15] = (bf16)p0[r];
        pw[(m * 16 + quad * 4 + r) * 40 + 16 + l15] = (bf16)p1[r];
      }
    }
    // issue V global loads BEFORE waiting on the P LDS round-trip
    bf16x8 vf[8];
    const bf16* vb_ = vbase0 + k0;
#pragma unroll
    for (int n = 0; n < 8; n++)
      vf[n] = *(const bf16x8*)(vb_ + (size_t)(n * 16 + l15) * SEQ + quad * 8);
    asm volatile("s_waitcnt lgkmcnt(0)" ::: "memory");
    bf16x8 pf[4];
#pragma unroll
    for (int m = 0; m < 4; m++)
      pf[m] = *(const bf16x8*)(pw + (m * 16 + l15) * 40 + quad * 8);
#pragma unroll
    for (int n = 0; n < 8; n++)
#pragma unroll
      for (int m = 0; m < 4; m++)
        o[m][n] = MFMA16(pf[m], vf[n], o[m][n]);
  }

  // l: reduce over the 16 key-columns per lane-group, then merge across waves
#pragma unroll
  for (int m = 0; m < 4; m++)
#pragma unroll
    for (int r = 0; r < 4; r++) {
      float v = lr[m][r];
      v += __shfl_xor(v, 1, 64);
      v += __shfl_xor(v, 2, 64);
      v += __shfl_xor(v, 4, 64);
      v += __shfl_xor(v, 8, 64);
      if (l15 == 0) atomicAdd(&lbuf[m * 16 + quad * 4 + r], v);
    }
  // O: linear merge across waves (fixed-max softmax => plain sum)
#pragma unroll
  for (int m = 0; m < 4; m++)
#pragma unroll
    for (int n = 0; n < 8; n++)
#pragma unroll
      for (int r = 0; r < 4; r++)
        atomicAdd(&Obuf[(m * 16 + quad * 4 + r) * 132 + n * 16 + l15], o[m][n][r]);
  __syncthreads();

  const int row = tid >> 2, d0 = (tid & 3) * 32;
  const float linv = 1.0f / lbuf[row];
  const float* ob = Obuf + row * 132 + d0;
  bf16* gp = Ob + (size_t)(qb0 + row) * 2048 + h * 128 + d0;
#pragma unroll
  for (int g = 0; g < 4; g++) {
    f32x4 a = *(const f32x4*)(ob + g * 8);
    f32x4 b = *(const f32x4*)(ob + g * 8 + 4);
    bf16x8 ov;
    ov[0] = (bf16)(a[0] * linv); ov[1] = (bf16)(a[1] * linv);
    ov[2] = (bf16)(a[2] * linv); ov[3] = (bf16)(a[3] * linv);
    ov[4] = (bf16)(b[0] * linv); ov[5] = (bf16)(b[1] * linv);
    ov[6] = (bf16)(b[2] * linv); ov[7] = (bf16)(b[3] * linv);
    *(bf16x8*)(gp + g * 8) = ov;
  }
}

// ---------------------------------------------------------------------------
// Orchestration
// ---------------------------------------------------------------------------
extern "C" void kernel_launch(void* const* d_in, const int* in_sizes, int n_in,
                              void* d_out, int out_size, void* d_ws, size_t ws_size,
                              hipStream_t stream) {
  const float* hid  = (const float*)d_in[0];
  const float* cosb = (const float*)d_in[1];
  const float* sinb = (const float*)d_in[2];
  const float* Wq   = (const float*)d_in[3];
  const float* Wk   = (const float*)d_in[4];
  const float* Wv   = (const float*)d_in[5];
  const float* Wo   = (const float*)d_in[6];
  const float* qw   = (const float*)d_in[7];
  const float* kw   = (const float*)d_in[8];

  if (ws_size < (size_t)(112u) * 1024u * 1024u) return;

  char* ws = (char*)d_ws;
  bf16* Xbf  = (bf16*)(ws);                         // 4096x2048 (16 MB); slot
  bf16* Vt   = (bf16*)(ws);                         //   reused for Vt after gemm1
  bf16* Wcat = (bf16*)(ws + (16u << 20));           // [Wq;Wk;Wv] 4096x2048
  bf16* Wob  = (bf16*)(ws + (32u << 20));           // 2048x2048 (8 MB)
  bf16* QKVb = (bf16*)(ws + (40u << 20));           // 4096x4096 (32 MB)
  bf16* Qb   = (bf16*)(ws + (72u << 20));           // [16][4096][128] (16 MB)
  bf16* Kb   = (bf16*)(ws + (88u << 20));           // [8][4096][128] (8 MB)
  bf16* Ob   = (bf16*)(ws + (96u << 20));           // 4096x2048 (16 MB)

  cvt_f32_bf16<<<8192, 256, 0, stream>>>(hid, Xbf, 2097152);
  cvt_f32_bf16<<<4096, 256, 0, stream>>>(Wq, Wcat, 1048576);
  cvt_f32_bf16<<<2048, 256, 0, stream>>>(Wk, Wcat + 4194304, 524288);
  cvt_f32_bf16<<<2048, 256, 0, stream>>>(Wv, Wcat + 6291456, 524288);
  cvt_f32_bf16<<<4096, 256, 0, stream>>>(Wo, Wob, 1048576);

  gemm_bt<bf16><<<dim3(32, 32), 256, 0, stream>>>(Xbf, Wcat, QKVb, 4096, 4096, 2048);
  vtrans<<<dim3(64, 8), 256, 0, stream>>>(QKVb, Vt);   // Xbf dead after gemm1
  normrope<<<24576, 256, 0, stream>>>(QKVb, cosb, sinb, qw, kw, Qb, Kb);
  attn_kernel<<<dim3(64, 16), 256, 0, stream>>>(Qb, Kb, Vt, Ob);
  gemm_bt<float><<<dim3(16, 32), 256, 0, stream>>>(Ob, Wob, (float*)d_out, 4096, 2048, 2048);
}

// Round 4
// 340.420 us; speedup vs baseline: 1.5737x; 1.5737x over previous
//
#include <hip/hip_runtime.h>

typedef __bf16 bf16;
typedef bf16 bf16x8 __attribute__((ext_vector_type(8)));
typedef bf16 bf16x4 __attribute__((ext_vector_type(4)));
typedef float f32x4 __attribute__((ext_vector_type(4)));

#define MFMA16(a, b, c) __builtin_amdgcn_mfma_f32_16x16x32_bf16((a), (b), (c), 0, 0, 0)

__device__ __forceinline__ void gload_lds16(const bf16* g, bf16* l) {
  __builtin_amdgcn_global_load_lds(
      (const __attribute__((address_space(1))) void*)g,
      (__attribute__((address_space(3))) void*)l, 16, 0, 0);
}

// ---------------------------------------------------------------------------
// fp32 -> bf16 convert
// ---------------------------------------------------------------------------
__global__ __launch_bounds__(256) void cvt_f32_bf16(const float* __restrict__ src,
                                                    bf16* __restrict__ dst, int n4) {
  int i = blockIdx.x * blockDim.x + threadIdx.x;
  if (i < n4) {
    float4 v = ((const float4*)src)[i];
    bf16x4 o;
    o[0] = (bf16)v.x; o[1] = (bf16)v.y; o[2] = (bf16)v.z; o[3] = (bf16)v.w;
    ((bf16x4*)dst)[i] = o;
  }
}

// ---------------------------------------------------------------------------
// GEMM C = A * B^T (m97 structure — unchanged, passing)
// ---------------------------------------------------------------------------
template <typename OutT>
__global__ __launch_bounds__(256) void gemm_bt(const bf16* __restrict__ A,
                                               const bf16* __restrict__ B,
                                               OutT* __restrict__ C,
                                               int M, int N, int K) {
  __shared__ __align__(16) bf16 As[128 * 64];
  __shared__ __align__(16) bf16 Bs[128 * 64];
  const int tid = threadIdx.x;
  const int w = tid >> 6, lane = tid & 63;
  const int l15 = lane & 15, quad = lane >> 4;
  const int m0 = blockIdx.y * 128, n0 = blockIdx.x * 128;
  const int wm = (w >> 1) * 64, wn = (w & 1) * 64;

  f32x4 acc[4][4] = {};

  for (int k0 = 0; k0 < K; k0 += 64) {
#pragma unroll
    for (int i = 0; i < 4; i++) {
      int s = w * 256 + i * 64 + lane;
      int row = s >> 3;
      int c8 = (s & 7) ^ (row & 7);
      gload_lds16(A + (size_t)(m0 + row) * K + k0 + c8 * 8, As + (w * 256 + i * 64) * 8);
    }
#pragma unroll
    for (int i = 0; i < 4; i++) {
      int s = w * 256 + i * 64 + lane;
      int row = s >> 3;
      int c8 = (s & 7) ^ (row & 7);
      gload_lds16(B + (size_t)(n0 + row) * K + k0 + c8 * 8, Bs + (w * 256 + i * 64) * 8);
    }
    __syncthreads();

#pragma unroll
    for (int kk = 0; kk < 2; kk++) {
      bf16x8 af[4], bfr[4];
#pragma unroll
      for (int mt = 0; mt < 4; mt++) {
        int row = wm + mt * 16 + l15;
        int slot = row * 8 + ((kk * 4 + quad) ^ (row & 7));
        af[mt] = *(const bf16x8*)(As + slot * 8);
      }
#pragma unroll
      for (int nt = 0; nt < 4; nt++) {
        int row = wn + nt * 16 + l15;
        int slot = row * 8 + ((kk * 4 + quad) ^ (row & 7));
        bfr[nt] = *(const bf16x8*)(Bs + slot * 8);
      }
#pragma unroll
      for (int mt = 0; mt < 4; mt++)
#pragma unroll
        for (int nt = 0; nt < 4; nt++)
          acc[mt][nt] = MFMA16(af[mt], bfr[nt], acc[mt][nt]);
    }
    __syncthreads();
  }

#pragma unroll
  for (int mt = 0; mt < 4; mt++)
#pragma unroll
    for (int nt = 0; nt < 4; nt++) {
      int row = m0 + wm + mt * 16 + quad * 4;
      int col = n0 + wn + nt * 16 + l15;
#pragma unroll
      for (int r = 0; r < 4; r++)
        C[(size_t)(row + r) * N + col] = (OutT)acc[mt][nt][r];
    }
}

// ---------------------------------------------------------------------------
// RMSNorm + RoPE. Q prescaled by D^-0.5 * log2(e) for fixed-max exp2 softmax
// (|score*log2e| <= 11.32*1.4427 < 17.3 by RMSNorm bound; M = 12*log2e).
// ---------------------------------------------------------------------------
__global__ __launch_bounds__(256) void normrope(const bf16* __restrict__ QKVb,
                                                const float* __restrict__ cosb,
                                                const float* __restrict__ sinb,
                                                const float* __restrict__ qw,
                                                const float* __restrict__ kw,
                                                bf16* __restrict__ Qb,
                                                bf16* __restrict__ Kb) {
  const int wid = (blockIdx.x * blockDim.x + threadIdx.x) >> 6;
  const int lane = threadIdx.x & 63;
  const int s = wid / 24;
  const int h = wid % 24;
  const bool isq = (h < 16);
  const int col0 = isq ? h * 128 : 2048 + (h - 16) * 128;
  const float* wt = isq ? qw : kw;

  const bf16* row = QKVb + (size_t)s * 4096 + col0;
  float x1 = (float)row[lane];
  float x2 = (float)row[lane + 64];

  float ss = x1 * x1 + x2 * x2;
#pragma unroll
  for (int m = 32; m >= 1; m >>= 1) ss += __shfl_xor(ss, m, 64);
  float rs = rsqrtf(ss * (1.0f / 128.0f) + 1e-6f);

  float c = cosb[(size_t)s * 128 + lane];
  float sn = sinb[(size_t)s * 128 + lane];
  float xn1 = x1 * rs * wt[lane];
  float xn2 = x2 * rs * wt[lane + 64];
  float o1 = xn1 * c - xn2 * sn;
  float o2 = xn2 * c + xn1 * sn;
  const float scale = isq ? 0.12751652f : 1.0f;  // D^-0.5 * log2(e)
  o1 *= scale; o2 *= scale;

  bf16* dst = isq ? (Qb + ((size_t)h * 4096 + s) * 128)
                  : (Kb + ((size_t)(h - 16) * 4096 + s) * 128);
  dst[lane] = (bf16)o1;
  dst[lane + 64] = (bf16)o2;
}

// ---------------------------------------------------------------------------
// V transpose + in-tile permute: Vtp[kvh][d][t*64 + kp] = V[t*64 + sig(kp)][d]
// with sig(kp) = (kp&3)*16 + (kp>>2). Matches attention's P layout kp=l15*4+c.
// ---------------------------------------------------------------------------
__global__ __launch_bounds__(256) void vtrans(const bf16* __restrict__ QKVb,
                                              bf16* __restrict__ Vtp) {
  __shared__ __align__(16) bf16 T[64 * 136];
  const int kvh = blockIdx.y;
  const int s0 = blockIdx.x * 64;   // one 64-key tile
  const int tid = threadIdx.x;
  for (int g = tid; g < 1024; g += 256) {
    int s = g >> 4, cg = g & 15;
    *(bf16x8*)(T + s * 136 + cg * 8) =
        *(const bf16x8*)(QKVb + (size_t)(s0 + s) * 4096 + 3072 + kvh * 128 + cg * 8);
  }
  __syncthreads();
  for (int g = tid; g < 1024; g += 256) {
    int d = g >> 3, sg = g & 7;
    bf16x8 v;
#pragma unroll
    for (int j = 0; j < 8; j++) {
      int kp = sg * 8 + j;
      int s = (kp & 3) * 16 + (kp >> 2);
      v[j] = T[s * 136 + d];
    }
    *(bf16x8*)(Vtp + ((size_t)kvh * 128 + d) * 4096 + s0 + sg * 8) = v;
  }
}

// ---------------------------------------------------------------------------
// Sliding-window GQA flash attention.
// 1-D grid 512, XCD-swizzled: kvh = id%8 so one KV head's blocks share an XCD
// (K+V = 2 MB fits the 4 MB per-XCD L2). Block = 128 q, 4 waves x 32 q.
// K-tile 64 keys; K/V staged via global_load_lds(16B) + XOR swizzle; fixed-max
// exp2 softmax (no running max / rescale); P round-trip per wave in LDS with
// permuted key order (kp = l15*4+c) so writes are single b64 stores.
// ---------------------------------------------------------------------------
__global__ __launch_bounds__(256, 2) void attn_kernel(const bf16* __restrict__ Qb,
                                                      const bf16* __restrict__ Kb,
                                                      const bf16* __restrict__ Vtp,
                                                      bf16* __restrict__ Ob) {
  const int SEQ = 4096, W = 1024;
  const float MP = 17.312340f;  // 12 * log2(e)
  __shared__ __align__(16) bf16 Ks[64 * 128];    // [key][d granule xor-swizzled]
  __shared__ __align__(16) bf16 Vs[128 * 64];    // [d][kp granule xor-swizzled]
  __shared__ __align__(16) bf16 Ps[4][32 * 64];  // per-wave P, xor-swizzled

  const int id = blockIdx.x;
  const int kvh = id & 7, gq = (id >> 3) & 1, h = kvh * 2 + gq;
  const int qb0 = (id >> 4) * 128;
  const int tid = threadIdx.x, w = tid >> 6, lane = tid & 63;
  const int l15 = lane & 15, quad = lane >> 4;
  const int qw0 = qb0 + w * 32;

  // Q fragments in registers: qf[m][kb], A-layout (m-row = l15, k = quad*8+j)
  bf16x8 qf[2][4];
#pragma unroll
  for (int m = 0; m < 2; m++) {
    const bf16* qp = Qb + ((size_t)h * SEQ + qw0 + m * 16 + l15) * 128 + quad * 8;
#pragma unroll
    for (int kb = 0; kb < 4; kb++) qf[m][kb] = *(const bf16x8*)(qp + kb * 32);
  }

  f32x4 o[2][8] = {};
  f32x4 lr[2] = {};
  bf16* pw = &Ps[w][0];
  const bf16* kbase = Kb + (size_t)kvh * SEQ * 128;
  const bf16* vbase = Vtp + (size_t)kvh * 128 * SEQ;

  int jmin = qb0 - (W - 1); if (jmin < 0) jmin = 0;
  const int kt0 = jmin >> 6, kt1 = (qb0 + 127) >> 6;

  for (int kt = kt0; kt <= kt1; ++kt) {
    const int k0 = kt * 64;
    // stage K tile: 1024 slots of 8 bf16, slot = key*16 + g, src granule g^(key&7)
#pragma unroll
    for (int i = 0; i < 4; i++) {
      int slot = w * 256 + i * 64 + lane;
      int key = slot >> 4, gg = slot & 15;
      int gsw = gg ^ (key & 7);
      gload_lds16(kbase + (size_t)(k0 + key) * 128 + gsw * 8, Ks + (w * 256 + i * 64) * 8);
    }
    // stage V tile: slot = d*8 + g, src granule g^(d&7), rows of Vtp contiguous
#pragma unroll
    for (int i = 0; i < 4; i++) {
      int slot = w * 256 + i * 64 + lane;
      int d = slot >> 3, gg = slot & 7;
      int gsw = gg ^ (d & 7);
      gload_lds16(vbase + (size_t)d * SEQ + k0 + gsw * 8, Vs + (w * 256 + i * 64) * 8);
    }
    __syncthreads();

    const bool alive = (k0 <= qw0 + 31) && (k0 + 63 > qw0 - W);
    if (alive) {
      const bool full = (k0 + 63 <= qw0) && (k0 > qw0 + 31 - W);
      // QK^T: s[m][c] covers q = qw0+m*16+quad*4+r, key = k0+c*16+l15
      f32x4 s[2][4] = {};
#pragma unroll
      for (int c = 0; c < 4; c++) {
        const int key = c * 16 + l15;
        bf16x8 kf[4];
#pragma unroll
        for (int kb = 0; kb < 4; kb++)
          kf[kb] = *(const bf16x8*)(Ks + key * 128 + (((kb * 4 + quad) ^ (key & 7)) << 3));
#pragma unroll
        for (int kb = 0; kb < 4; kb++) {
          s[0][c] = MFMA16(qf[0][kb], kf[kb], s[0][c]);
          s[1][c] = MFMA16(qf[1][kb], kf[kb], s[1][c]);
        }
      }
      // exp2 (fixed max), accumulate l, pack P (kp = l15*4 + c) as b64 stores
#pragma unroll
      for (int m = 0; m < 2; m++)
#pragma unroll
        for (int r = 0; r < 4; r++) {
          float p[4];
          if (full) {
#pragma unroll
            for (int c = 0; c < 4; c++) p[c] = __builtin_amdgcn_exp2f(s[m][c][r] - MP);
          } else {
            const int i_ = qw0 + m * 16 + quad * 4 + r;
#pragma unroll
            for (int c = 0; c < 4; c++) {
              int j = k0 + c * 16 + l15;
              p[c] = (j <= i_ && j > i_ - W) ? __builtin_amdgcn_exp2f(s[m][c][r] - MP) : 0.0f;
            }
          }
          lr[m][r] += p[0] + p[1] + p[2] + p[3];
          bf16x4 pk;
          pk[0] = (bf16)p[0]; pk[1] = (bf16)p[1]; pk[2] = (bf16)p[2]; pk[3] = (bf16)p[3];
          const int q = m * 16 + quad * 4 + r;
          *(bf16x4*)(pw + q * 64 + (((l15 >> 1) ^ (q & 7)) << 3) + (l15 & 1) * 4) = pk;
        }
      asm volatile("s_waitcnt lgkmcnt(0)" ::: "memory");
      // P A-frags (row = m*16+l15, kp = kb*32+quad*8) and PV
      bf16x8 pf[2][2];
#pragma unroll
      for (int m = 0; m < 2; m++)
#pragma unroll
        for (int kb = 0; kb < 2; kb++)
          pf[m][kb] = *(const bf16x8*)(pw + (m * 16 + l15) * 64 +
                                       (((kb * 4 + quad) ^ (l15 & 7)) << 3));
#pragma unroll
      for (int n = 0; n < 8; n++) {
        const int d = n * 16 + l15;
        bf16x8 vf0 = *(const bf16x8*)(Vs + d * 64 + ((quad ^ (l15 & 7)) << 3));
        bf16x8 vf1 = *(const bf16x8*)(Vs + d * 64 + (((4 + quad) ^ (l15 & 7)) << 3));
        o[0][n] = MFMA16(pf[0][0], vf0, o[0][n]);
        o[0][n] = MFMA16(pf[0][1], vf1, o[0][n]);
        o[1][n] = MFMA16(pf[1][0], vf0, o[1][n]);
        o[1][n] = MFMA16(pf[1][1], vf1, o[1][n]);
      }
    }
    __syncthreads();
  }

  // l: reduce partials over the 16 l15 columns (once, at the end)
  float linv[2][4];
#pragma unroll
  for (int m = 0; m < 2; m++)
#pragma unroll
    for (int r = 0; r < 4; r++) {
      float v = lr[m][r];
      v += __shfl_xor(v, 1, 64);
      v += __shfl_xor(v, 2, 64);
      v += __shfl_xor(v, 4, 64);
      v += __shfl_xor(v, 8, 64);
      linv[m][r] = 1.0f / v;
    }
#pragma unroll
  for (int m = 0; m < 2; m++)
#pragma unroll
    for (int n = 0; n < 8; n++)
#pragma unroll
      for (int r = 0; r < 4; r++) {
        int i_ = qw0 + m * 16 + quad * 4 + r;
        Ob[(size_t)i_ * 2048 + h * 128 + n * 16 + l15] = (bf16)(o[m][n][r] * linv[m][r]);
      }
}

// ---------------------------------------------------------------------------
// Orchestration
// ---------------------------------------------------------------------------
extern "C" void kernel_launch(void* const* d_in, const int* in_sizes, int n_in,
                              void* d_out, int out_size, void* d_ws, size_t ws_size,
                              hipStream_t stream) {
  const float* hid  = (const float*)d_in[0];
  const float* cosb = (const float*)d_in[1];
  const float* sinb = (const float*)d_in[2];
  const float* Wq   = (const float*)d_in[3];
  const float* Wk   = (const float*)d_in[4];
  const float* Wv   = (const float*)d_in[5];
  const float* Wo   = (const float*)d_in[6];
  const float* qw   = (const float*)d_in[7];
  const float* kw   = (const float*)d_in[8];

  if (ws_size < (size_t)(112u) * 1024u * 1024u) return;

  char* ws = (char*)d_ws;
  bf16* Xbf  = (bf16*)(ws);                         // 4096x2048 (16 MB); slot
  bf16* Vtp  = (bf16*)(ws);                         //   reused for Vtp after gemm1
  bf16* Wcat = (bf16*)(ws + (16u << 20));           // [Wq;Wk;Wv] 4096x2048
  bf16* Wob  = (bf16*)(ws + (32u << 20));           // 2048x2048 (8 MB)
  bf16* QKVb = (bf16*)(ws + (40u << 20));           // 4096x4096 (32 MB)
  bf16* Qb   = (bf16*)(ws + (72u << 20));           // [16][4096][128] (16 MB)
  bf16* Kb   = (bf16*)(ws + (88u << 20));           // [8][4096][128] (8 MB)
  bf16* Ob   = (bf16*)(ws + (96u << 20));           // 4096x2048 (16 MB)

  cvt_f32_bf16<<<8192, 256, 0, stream>>>(hid, Xbf, 2097152);
  cvt_f32_bf16<<<4096, 256, 0, stream>>>(Wq, Wcat, 1048576);
  cvt_f32_bf16<<<2048, 256, 0, stream>>>(Wk, Wcat + 4194304, 524288);
  cvt_f32_bf16<<<2048, 256, 0, stream>>>(Wv, Wcat + 6291456, 524288);
  cvt_f32_bf16<<<4096, 256, 0, stream>>>(Wo, Wob, 1048576);

  gemm_bt<bf16><<<dim3(32, 32), 256, 0, stream>>>(Xbf, Wcat, QKVb, 4096, 4096, 2048);
  vtrans<<<dim3(64, 8), 256, 0, stream>>>(QKVb, Vtp);   // Xbf dead after gemm1
  normrope<<<24576, 256, 0, stream>>>(QKVb, cosb, sinb, qw, kw, Qb, Kb);
  attn_kernel<<<512, 256, 0, stream>>>(Qb, Kb, Vtp, Ob);
  gemm_bt<float><<<dim3(16, 32), 256, 0, stream>>>(Ob, Wob, (float*)d_out, 4096, 2048, 2048);
}